// Round 2
// baseline (530.837 us; speedup 1.0000x reference)
//
#include <hip/hip_runtime.h>
#include <math.h>

namespace {

constexpr int CCH = 128;      // number of classes C (fixed by problem)
constexpr int LROW = CCH + 4; // LDS row stride in floats (132): [128] is zero sentinel
constexpr int CH = 8;         // time rows per staged chunk
constexpr int PL = 9;         // s-states per lane (64*9 = 576 >= 513)
constexpr int BLANK = 1;

__global__ __launch_bounds__(64, 1)
void ctc_fwd(const float* __restrict__ lp,
             const int* __restrict__ ilen,
             const int* __restrict__ tgt,
             const int* __restrict__ tlen,
             float* __restrict__ perb,
             int T, int B, int L)
{
    const int b = blockIdx.x;
    const int lane = threadIdx.x;                 // 0..63, single wave
    int Tb = ilen[b];  if (Tb < 1) Tb = 1;  if (Tb > T) Tb = T;
    int U  = tlen[b];  if (U < 0) U = 0;    if (U > L) U = L;
    const int SE = 2 * L + 1;                     // 513 for L=256

    __shared__ float pbuf[2][CH][LROW];
    __shared__ double afin[64 * PL];

    // zero the sentinel column (gathers with index CCH read 0 -> dead states)
    if (lane < 16) pbuf[lane >> 3][lane & 7][CCH] = 0.0f;

    // ---- per-lane extended labels & skip masks -------------------------
    const int s0 = lane * PL;
    int ext[PL];
    double skipm[PL];
#pragma unroll
    for (int j = 0; j < PL; ++j) {
        const int s = s0 + j;
        int e;
        if (s >= SE) e = CCH;                     // sentinel -> p = 0
        else if ((s & 1) == 0) e = BLANK;
        else {
            const int pos = s >> 1;
            e = (pos < U) ? tgt[b * L + pos] : BLANK;
        }
        ext[j] = e;
    }
#pragma unroll
    for (int j = 0; j < PL; ++j) {
        const int s = s0 + j;
        double m = 0.0;
        if (s < SE && (s & 1) && ext[j] != BLANK) {
            int eprev = BLANK;
            const int sp = s - 2;
            if (sp >= 1) {
                const int pos = sp >> 1;
                eprev = (pos < U) ? tgt[b * L + pos] : BLANK;
            }
            m = (ext[j] != eprev) ? 1.0 : 0.0;
        }
        skipm[j] = m;
    }

    // ---- staging machinery --------------------------------------------
    const float* base = lp + (size_t)b * CCH;
    const size_t rowstride = (size_t)B * CCH;

    float2 rA[CH], rB[CH];
    double sblank = 0.0;   // uniform across lanes
    int logz = 0;          // uniform across lanes
    double a[PL];

    auto issue = [&](float2* r, int chunk) {
#pragma unroll
        for (int i = 0; i < CH; ++i) {
            int t = chunk * CH + i;
            t = (t < T) ? t : (T - 1);
            r[i] = *reinterpret_cast<const float2*>(base + (size_t)t * rowstride + 2 * lane);
        }
    };

    auto stage = [&](const float2* r, int buf, int chunk) {
#pragma unroll
        for (int i = 0; i < CH; ++i) {
            const float2 v = r[i];
            const float lpb = __shfl(v.y, 0);     // element index 1 = blank logprob
            const int t = chunk * CH + i;
            if (t < Tb) sblank += (double)lpb;    // uniform
            float2 p;
            p.x = __expf(v.x - lpb);
            p.y = __expf(v.y - lpb);
            *reinterpret_cast<float2*>(&pbuf[buf][i][2 * lane]) = p;
        }
    };

    auto step = [&](int buf, int r) {
        float pj[PL];
#pragma unroll
        for (int j = 0; j < PL; ++j) pj[j] = pbuf[buf][r][ext[j]];
        double am1 = __shfl_up(a[PL - 1], 1);     // alpha[s0-1]
        double am2 = __shfl_up(a[PL - 2], 1);     // alpha[s0-2]
        if (lane == 0) { am1 = 0.0; am2 = 0.0; }
        double nn[PL];
        nn[0] = (a[0] + am1 + skipm[0] * am2) * (double)pj[0];
        nn[1] = (a[1] + a[0] + skipm[1] * am1) * (double)pj[1];
#pragma unroll
        for (int j = 2; j < PL; ++j)
            nn[j] = (a[j] + a[j - 1] + skipm[j] * a[j - 2]) * (double)pj[j];
#pragma unroll
        for (int j = 0; j < PL; ++j) a[j] = nn[j];
    };

    auto rescale = [&]() {
        double m = a[0];
#pragma unroll
        for (int j = 1; j < PL; ++j) m = fmax(m, a[j]);
#pragma unroll
        for (int off = 32; off >= 1; off >>= 1) m = fmax(m, __shfl_xor(m, off));
        if (m > 0.0) {
            int e = (int)((__double_as_longlong(m) >> 52) & 0x7FF);
            if (e == 0) e = 1;
            const double sc = __longlong_as_double((long long)(2046 - e) << 52); // 2^(1023-e)
#pragma unroll
            for (int j = 0; j < PL; ++j) a[j] *= sc;
            logz += e - 1023;
        }
    };

    // ---- prologue ------------------------------------------------------
    issue(rA, 0);
    issue(rB, 1);
    stage(rA, 0, 0);
    __syncthreads();   // one-time: make staged chunk 0 + sentinel visible

#pragma unroll
    for (int j = 0; j < PL; ++j) a[j] = 0.0;
    if (lane == 0) {
        a[0] = 1.0;                           // p_adj(blank) at t=0
        a[1] = (double)pbuf[0][0][ext[1]];    // p_adj(first label) at t=0
    }

    const int nch = (Tb + CH - 1) / CH;

    // ---- main pipelined loop: 2 chunks per iteration -------------------
    for (int c = 0; c < nch; c += 2) {
        issue(rA, c + 2);
#pragma unroll
        for (int r = 0; r < CH; ++r) {
            const int t = c * CH + r;
            if (t == 0) continue;
            if (t < Tb) step(0, r);
        }
        rescale();
        if (c + 1 < nch) {
            stage(rB, 1, c + 1);
            issue(rB, c + 3);
#pragma unroll
            for (int r = 0; r < CH; ++r) {
                const int t = (c + 1) * CH + r;
                if (t < Tb) step(1, r);
            }
            rescale();
            if (c + 2 < nch) stage(rA, 0, c + 2);
        }
    }

    // ---- epilogue: extract ll -----------------------------------------
#pragma unroll
    for (int j = 0; j < PL; ++j) afin[s0 + j] = a[j];
    __syncthreads();
    if (lane == 0) {
        const int i1 = 2 * U;
        int i2 = 2 * U - 1; if (i2 < 0) i2 = 0;
        const double ssum = afin[i1] + afin[i2];
        const double ll = log(ssum) + sblank + (double)logz * 0.6931471805599453;
        perb[b] = (float)(-ll);
    }
}

__global__ void reduce_sum(const float* __restrict__ perb, float* __restrict__ out, int B)
{
    const int lane = threadIdx.x;
    float v = 0.0f;
    for (int i = lane; i < B; i += 64) v += perb[i];
#pragma unroll
    for (int off = 32; off >= 1; off >>= 1) v += __shfl_xor(v, off);
    if (lane == 0) out[0] = v;
}

} // namespace

extern "C" void kernel_launch(void* const* d_in, const int* in_sizes, int n_in,
                              void* d_out, int out_size, void* d_ws, size_t ws_size,
                              hipStream_t stream)
{
    const float* lp  = (const float*)d_in[0];   // [T,B,C] log-softmax, f32
    const int* ilen  = (const int*)d_in[1];     // [B]
    const int* tgt   = (const int*)d_in[2];     // [B,L]
    const int* tlen  = (const int*)d_in[3];     // [B]

    const int B = in_sizes[1];
    const int L = in_sizes[2] / B;
    const int T = in_sizes[0] / (B * CCH);

    float* perb = (float*)d_ws;

    ctc_fwd<<<B, 64, 0, stream>>>(lp, ilen, tgt, tlen, perb, T, B, L);
    reduce_sum<<<1, 64, 0, stream>>>(perb, (float*)d_out, B);
}

// Round 3
// 289.949 us; speedup vs baseline: 1.8308x; 1.8308x over previous
//
#include <hip/hip_runtime.h>
#include <math.h>

namespace {

constexpr int CCH = 128;   // classes
constexpr int ROWD = 128;  // doubles per LDS p-row
constexpr int CH = 8;      // time rows per staged chunk
constexpr int PL = 8;      // s-states per lane (64*8 = 512; s=512 handled as scalar)
constexpr int BLANK = 1;

__device__ __forceinline__ int imax(int a, int b) { return a > b ? a : b; }

// lane i <- lane i-1 (lane 0 <- 0.0), pure VALU (DPP wave_shr:1)
__device__ __forceinline__ double dpp_shr1_f64(double x) {
    int lo = __double2loint(x), hi = __double2hiint(x);
    lo = __builtin_amdgcn_update_dpp(0, lo, 0x138, 0xF, 0xF, true);
    hi = __builtin_amdgcn_update_dpp(0, hi, 0x138, 0xF, 0xF, true);
    return __hiloint2double(hi, lo);
}

__global__ __launch_bounds__(64, 1)
void ctc_fwd(const float* __restrict__ lp,
             const int* __restrict__ ilen,
             const int* __restrict__ tgt,
             const int* __restrict__ tlen,
             float* __restrict__ perb,
             int T, int B, int L)
{
    const int b = blockIdx.x;
    const int lane = threadIdx.x;                 // single wave
    int Tb = ilen[b]; if (Tb < 1) Tb = 1; if (Tb > T) Tb = T;
    int U  = tlen[b]; if (U < 0) U = 0;   if (U > L) U = L;

    __shared__ double pbuf[2][CH][ROWD];          // p_adj (blank-normalized), f64
    __shared__ double afin[2 * 256 + 2];          // final alpha (513 + pad)

    // ---- per-lane odd-state labels: pos = lane*4 + k  (covers 0..255) ----
    const int4 lab4 = *reinterpret_cast<const int4*>(tgt + (size_t)b * L + lane * 4);
    const int labs[4] = {lab4.x, lab4.y, lab4.z, lab4.w};
    const int prevlast = __shfl_up(labs[3], 1);   // label at pos-1 for k=0
    int ext[4];
    double skipm[4];
#pragma unroll
    for (int k = 0; k < 4; ++k) {
        const int pos = lane * 4 + k;
        ext[k] = (pos < U) ? labs[k] : BLANK;
        const int prev = (k == 0) ? ((pos >= 1) ? prevlast : BLANK)
                                  : labs[k - 1];
        const int eprev = (pos >= 1 && pos - 1 < U) ? prev : BLANK;
        skipm[k] = (ext[k] != BLANK && ext[k] != eprev) ? 1.0 : 0.0;
    }

    // ---- staging machinery ---------------------------------------------
    const float* base = lp + (size_t)b * CCH;
    const size_t rowstride = (size_t)B * CCH;

    float2 rA[CH], rB[CH];
    double sblank = 0.0;   // uniform
    int logz = 0;          // uniform
    double a[PL];
    double a512 = 0.0;     // only lane 63's copy is meaningful
    double G[CH][4];

    auto issue = [&](float2* r, int chunk) {
#pragma unroll
        for (int i = 0; i < CH; ++i) {
            int t = chunk * CH + i;
            t = (t < T) ? t : (T - 1);
            r[i] = *reinterpret_cast<const float2*>(base + (size_t)t * rowstride + 2 * lane);
        }
    };

    auto stage = [&](const float2* r, int buf, int chunk) {
#pragma unroll
        for (int i = 0; i < CH; ++i) {
            const float2 v = r[i];
            const float lpb = __int_as_float(
                __builtin_amdgcn_readfirstlane(__float_as_int(v.y))); // class 1 = blank
            const int t = chunk * CH + i;
            if (t < Tb) sblank += (double)lpb;    // uniform
            double2 p;
            p.x = (double)__expf(v.x - lpb);
            p.y = (double)__expf(v.y - lpb);
            *reinterpret_cast<double2*>(&pbuf[buf][i][2 * lane]) = p;
        }
    };

    auto gather = [&](int buf) {
#pragma unroll
        for (int r = 0; r < CH; ++r)
#pragma unroll
            for (int k = 0; k < 4; ++k)
                G[r][k] = pbuf[buf][r][ext[k]];
    };

    // one time step; even j = blank (p==1, no skip), odd j = label
    auto step = [&](const double* g) {
        const double am1 = dpp_shr1_f64(a[7]);    // alpha[s0-1] (lane0 -> 0)
        a512 += a[7];                             // uses pre-update a[7]
        const double n0 = a[0] + am1;
        const double n1 = (a[1] + a[0] + skipm[0] * am1) * g[0];
        const double n2 = a[2] + a[1];
        const double n3 = (a[3] + a[2] + skipm[1] * a[1]) * g[1];
        const double n4 = a[4] + a[3];
        const double n5 = (a[5] + a[4] + skipm[2] * a[3]) * g[2];
        const double n6 = a[6] + a[5];
        const double n7 = (a[7] + a[6] + skipm[3] * a[5]) * g[3];
        a[0] = n0; a[1] = n1; a[2] = n2; a[3] = n3;
        a[4] = n4; a[5] = n5; a[6] = n6; a[7] = n7;
    };

    // exact power-of-2 rescale; max via DPP row_shr reduce (no LDS)
    auto rescale = [&]() {
        double m = fmax(fmax(fmax(a[0], a[1]), fmax(a[2], a[3])),
                        fmax(fmax(a[4], a[5]), fmax(a[6], a[7])));
        int v = __float_as_int((float)m);         // positive floats: int-max == fp-max
        int t;
        t = __builtin_amdgcn_update_dpp(0, v, 0x111, 0xF, 0xF, true); v = imax(v, t);
        t = __builtin_amdgcn_update_dpp(0, v, 0x112, 0xF, 0xF, true); v = imax(v, t);
        t = __builtin_amdgcn_update_dpp(0, v, 0x114, 0xF, 0xF, true); v = imax(v, t);
        t = __builtin_amdgcn_update_dpp(0, v, 0x118, 0xF, 0xF, true); v = imax(v, t);
        const int m0 = __builtin_amdgcn_readlane(v, 15);
        const int m1 = __builtin_amdgcn_readlane(v, 31);
        const int m2 = __builtin_amdgcn_readlane(v, 47);
        const int m3 = __builtin_amdgcn_readlane(v, 63);
        const int mb = imax(imax(m0, m1), imax(m2, m3));
        const int e32 = (mb >> 23) & 0xFF;
        if (e32 > 0) {
            const double sc = __hiloint2double((1150 - e32) << 20, 0); // 2^(127-e32)... exact
#pragma unroll
            for (int j = 0; j < PL; ++j) a[j] *= sc;
            a512 *= sc;
            logz += e32 - 127;
        }
    };

    // ---- prologue --------------------------------------------------------
    issue(rA, 0);
    issue(rB, 1);
    stage(rA, 0, 0);
    issue(rA, 2);
#pragma unroll
    for (int j = 0; j < PL; ++j) a[j] = 0.0;

    const int nch = (Tb + CH - 1) / CH;

    // ---- main loop: 1 chunk per iteration, rescale every 2 chunks --------
    for (int c = 0; c < nch; ++c) {
        const int buf = c & 1;
        gather(buf);                               // 32x ds_read_b64, off-chain
        if (c + 1 < nch) {
            if ((c + 1) & 1) { stage(rB, 1, c + 1); issue(rB, c + 3); }
            else             { stage(rA, 0, c + 1); issue(rA, c + 3); }
        }
        const int t0 = c * CH;
        if (c == 0) {
            if (lane == 0) { a[0] = 1.0; a[1] = G[0][0]; }   // t=0 init
#pragma unroll
            for (int r = 1; r < CH; ++r) if (r < Tb) step(G[r]);
        } else if (t0 + CH <= Tb) {
#pragma unroll
            for (int r = 0; r < CH; ++r) step(G[r]);         // fast path, no guards
        } else {
#pragma unroll
            for (int r = 0; r < CH; ++r) if (t0 + r < Tb) step(G[r]);
        }
        if ((c & 1) || (c == nch - 1)) rescale();
    }

    // ---- epilogue ---------------------------------------------------------
#pragma unroll
    for (int j = 0; j < PL; ++j) afin[lane * PL + j] = a[j];
    if (lane == 63) afin[512] = a512;
    __syncthreads();
    if (lane == 0) {
        const int i1 = 2 * U;
        int i2 = 2 * U - 1; if (i2 < 0) i2 = 0;
        const double ssum = afin[i1] + afin[i2];
        const double ll = log(ssum) + sblank + (double)logz * 0.6931471805599453;
        perb[b] = (float)(-ll);
    }
}

__global__ void reduce_sum(const float* __restrict__ perb, float* __restrict__ out, int B)
{
    const int lane = threadIdx.x;
    float v = 0.0f;
    for (int i = lane; i < B; i += 64) v += perb[i];
#pragma unroll
    for (int off = 32; off >= 1; off >>= 1) v += __shfl_xor(v, off);
    if (lane == 0) out[0] = v;
}

} // namespace

extern "C" void kernel_launch(void* const* d_in, const int* in_sizes, int n_in,
                              void* d_out, int out_size, void* d_ws, size_t ws_size,
                              hipStream_t stream)
{
    const float* lp  = (const float*)d_in[0];   // [T,B,C] log-softmax, f32
    const int* ilen  = (const int*)d_in[1];     // [B]
    const int* tgt   = (const int*)d_in[2];     // [B,L]
    const int* tlen  = (const int*)d_in[3];     // [B]

    const int B = in_sizes[1];
    const int L = in_sizes[2] / B;
    const int T = in_sizes[0] / (B * CCH);

    float* perb = (float*)d_ws;

    ctc_fwd<<<B, 64, 0, stream>>>(lp, ilen, tgt, tlen, perb, T, B, L);
    reduce_sum<<<1, 64, 0, stream>>>(perb, (float*)d_out, B);
}

// Round 4
// 184.819 us; speedup vs baseline: 2.8722x; 1.5688x over previous
//
#include <hip/hip_runtime.h>
#include <math.h>

namespace {

constexpr int CCH = 128;   // classes
constexpr int BLANK = 1;
constexpr int CH = 16;     // scan steps per chunk (register double-buffer)
constexpr int GT = 8;      // pass-1 time rows per block

__device__ __forceinline__ int imax(int a, int b) { return a > b ? a : b; }

// lane i <- lane i-1 (lane 0 <- 0.0), pure VALU (DPP wave_shr:1)
__device__ __forceinline__ double dpp_shr1_f64(double x) {
    int lo = __double2loint(x), hi = __double2hiint(x);
    lo = __builtin_amdgcn_update_dpp(0, lo, 0x138, 0xF, 0xF, true);
    hi = __builtin_amdgcn_update_dpp(0, hi, 0x138, 0xF, 0xF, true);
    return __hiloint2double(hi, lo);
}

// ---------------- pass 1: parallel gather/exp ----------------
__global__ __launch_bounds__(256)
void ctc_gather(const float* __restrict__ lp,
                const int* __restrict__ tgt,
                const int* __restrict__ tlen,
                float* __restrict__ gout,   // [B][T][256]
                float* __restrict__ lpbout, // [B][T]
                int T, int B, int L)
{
    const int b   = blockIdx.y;
    const int t0  = blockIdx.x * GT;
    const int tid = threadIdx.x;

    __shared__ int   sTgt[256];
    __shared__ float sLp[GT][CCH];

    int U = tlen[b]; if (U < 0) U = 0; if (U > L) U = L;

    sTgt[tid] = tgt[(size_t)b * L + tid];
    {
        const int idx = tid * 4;
        const int r = idx >> 7, col = idx & 127;
        *reinterpret_cast<float4*>(&sLp[r][col]) =
            *reinterpret_cast<const float4*>(lp + ((size_t)(t0 + r) * B + b) * CCH + col);
    }
    __syncthreads();

    const int r = tid >> 5;          // 0..7 : time row
    const int c = tid & 31;          // 0..31: position group
    const float blankv = sLp[r][BLANK];
    float g[8];
#pragma unroll
    for (int k = 0; k < 8; ++k) {
        const int p = c * 8 + k;
        const int lab = (p < U) ? (sTgt[p] & 127) : BLANK;
        g[k] = __expf(sLp[r][lab] - blankv);   // pos>=U -> expf(0)=1 exactly
    }
    float* dst = gout + ((size_t)b * T + (t0 + r)) * 256 + c * 8;
    *reinterpret_cast<float4*>(dst)     = make_float4(g[0], g[1], g[2], g[3]);
    *reinterpret_cast<float4*>(dst + 4) = make_float4(g[4], g[5], g[6], g[7]);
    if (tid < GT) lpbout[(size_t)b * T + t0 + tid] = sLp[tid][BLANK];
}

// ---------------- pass 2: serial scan, no LDS in hot loop ----------------
__global__ __launch_bounds__(64, 1)
void ctc_scan(const float* __restrict__ gg,   // [B][T][256]
              const float* __restrict__ lpb,  // [B][T]
              const int* __restrict__ ilen,
              const int* __restrict__ tgt,
              const int* __restrict__ tlen,
              float* __restrict__ perb,
              int T, int B, int L)
{
    const int b = blockIdx.x;
    const int lane = threadIdx.x;
    int Tb = ilen[b]; if (Tb < 1) Tb = 1; if (Tb > T) Tb = T;
    int U  = tlen[b]; if (U < 0) U = 0;   if (U > L) U = L;

    __shared__ double afin[514];

    // ---- per-lane skip masks (pos = lane*4 + k) ----
    const int4 lab4 = *reinterpret_cast<const int4*>(tgt + (size_t)b * L + lane * 4);
    const int labs[4] = {lab4.x, lab4.y, lab4.z, lab4.w};
    const int prevlast = __shfl_up(labs[3], 1);
    double skipm[4];
#pragma unroll
    for (int k = 0; k < 4; ++k) {
        const int pos = lane * 4 + k;
        const int e = (pos < U) ? labs[k] : BLANK;
        const int prevraw = (k == 0) ? ((pos >= 1) ? prevlast : BLANK) : labs[k - 1];
        const int eprev = (pos >= 1 && pos - 1 < U) ? prevraw : BLANK;
        skipm[k] = (e != BLANK && e != eprev) ? 1.0 : 0.0;
    }

    const float* gb = gg + (size_t)b * T * 256 + lane * 4;

    double a[8];
#pragma unroll
    for (int j = 0; j < 8; ++j) a[j] = 0.0;
    double a512 = 0.0;     // lane 63's copy = alpha[512]
    int logz = 0;

    float4 GA[CH], GB[CH];

    auto issue = [&](float4* Gx, int chunk) {
#pragma unroll
        for (int r = 0; r < CH; ++r) {
            int t = chunk * CH + r;
            t = (t < T) ? t : (T - 1);
            Gx[r] = *reinterpret_cast<const float4*>(gb + (size_t)t * 256);
        }
    };

    auto step = [&](const float4 gf) {
        const double g0 = (double)gf.x, g1 = (double)gf.y,
                     g2 = (double)gf.z, g3 = (double)gf.w;
        const double am1 = dpp_shr1_f64(a[7]);   // alpha[s0-1] (lane0 -> 0)
        a512 += a[7];                            // pre-update a[7] (lane63 = alpha[511])
        const double n0 = a[0] + am1;
        const double n1 = (a[1] + a[0] + skipm[0] * am1) * g0;
        const double n2 = a[2] + a[1];
        const double n3 = (a[3] + a[2] + skipm[1] * a[1]) * g1;
        const double n4 = a[4] + a[3];
        const double n5 = (a[5] + a[4] + skipm[2] * a[3]) * g2;
        const double n6 = a[6] + a[5];
        const double n7 = (a[7] + a[6] + skipm[3] * a[5]) * g3;
        a[0] = n0; a[1] = n1; a[2] = n2; a[3] = n3;
        a[4] = n4; a[5] = n5; a[6] = n6; a[7] = n7;
    };

    // exact power-of-2 rescale; max via f64 hi-word int reduce (no LDS, no f32 range limit)
    auto rescale = [&]() {
        double m = fmax(fmax(fmax(a[0], a[1]), fmax(a[2], a[3])),
                        fmax(fmax(a[4], a[5]), fmax(a[6], a[7])));
        int v = __double2hiint(m);               // nonneg doubles: hi-word int order = fp order
        int t;
        t = __builtin_amdgcn_update_dpp(0, v, 0x111, 0xF, 0xF, true); v = imax(v, t);
        t = __builtin_amdgcn_update_dpp(0, v, 0x112, 0xF, 0xF, true); v = imax(v, t);
        t = __builtin_amdgcn_update_dpp(0, v, 0x114, 0xF, 0xF, true); v = imax(v, t);
        t = __builtin_amdgcn_update_dpp(0, v, 0x118, 0xF, 0xF, true); v = imax(v, t);
        const int m0 = __builtin_amdgcn_readlane(v, 15);
        const int m1 = __builtin_amdgcn_readlane(v, 31);
        const int m2 = __builtin_amdgcn_readlane(v, 47);
        const int m3 = __builtin_amdgcn_readlane(v, 63);
        const int mb = imax(imax(m0, m1), imax(m2, m3));
        const int e11 = (mb >> 20) & 0x7FF;
        if (e11 > 0) {
            const double sc = __hiloint2double((2046 - e11) << 20, 0);  // 2^(1023-e11)
#pragma unroll
            for (int j = 0; j < 8; ++j) a[j] *= sc;
            a512 *= sc;
            logz += e11 - 1023;
        }
    };

    auto chunk = [&](float4 (&Gx)[CH], int c) {
        const int t0 = c * CH;
        if (c == 0) {
            if (lane == 0) { a[0] = 1.0; a[1] = (double)Gx[0].x; }  // t=0 init
#pragma unroll
            for (int r = 1; r < CH; ++r) if (r < Tb) step(Gx[r]);
        } else if (t0 + CH <= Tb) {
#pragma unroll
            for (int r = 0; r < CH; ++r) step(Gx[r]);               // fast path
        } else {
#pragma unroll
            for (int r = 0; r < CH; ++r) if (t0 + r < Tb) step(Gx[r]);
        }
    };

    const int nch = (Tb + CH - 1) / CH;

    issue(GA, 0);
    issue(GB, 1);

    for (int c = 0; c < nch; c += 2) {
        chunk(GA, c);
        issue(GA, c + 2);
        rescale();
        if (c + 1 < nch) {
            chunk(GB, c + 1);
            issue(GB, c + 3);
            rescale();
        }
    }

    // ---- epilogue ----
#pragma unroll
    for (int j = 0; j < 8; ++j) afin[lane * 8 + j] = a[j];
    if (lane == 63) afin[512] = a512;

    // sblank: coalesced read of lpb, deterministic butterfly reduce (f64)
    double sb = 0.0;
    const float* lbp = lpb + (size_t)b * T;
    for (int i = lane; i < T; i += 64)
        if (i < Tb) sb += (double)lbp[i];
#pragma unroll
    for (int off = 32; off >= 1; off >>= 1) sb += __shfl_xor(sb, off);

    __syncthreads();
    if (lane == 0) {
        const int i1 = 2 * U;
        int i2 = 2 * U - 1; if (i2 < 0) i2 = 0;
        const double ssum = afin[i1] + afin[i2];
        const double ll = log(ssum) + sb + (double)logz * 0.6931471805599453;
        perb[b] = (float)(-ll);
    }
}

// ---------------- fallback: proven round-3 single-kernel path ----------------
constexpr int FCH = 8;
constexpr int ROWD = 128;

__global__ __launch_bounds__(64, 1)
void ctc_fwd(const float* __restrict__ lp,
             const int* __restrict__ ilen,
             const int* __restrict__ tgt,
             const int* __restrict__ tlen,
             float* __restrict__ perb,
             int T, int B, int L)
{
    const int b = blockIdx.x;
    const int lane = threadIdx.x;
    int Tb = ilen[b]; if (Tb < 1) Tb = 1; if (Tb > T) Tb = T;
    int U  = tlen[b]; if (U < 0) U = 0;   if (U > L) U = L;

    __shared__ double pbuf[2][FCH][ROWD];
    __shared__ double afin[2 * 256 + 2];

    const int4 lab4 = *reinterpret_cast<const int4*>(tgt + (size_t)b * L + lane * 4);
    const int labs[4] = {lab4.x, lab4.y, lab4.z, lab4.w};
    const int prevlast = __shfl_up(labs[3], 1);
    int ext[4];
    double skipm[4];
#pragma unroll
    for (int k = 0; k < 4; ++k) {
        const int pos = lane * 4 + k;
        ext[k] = (pos < U) ? labs[k] : BLANK;
        const int prev = (k == 0) ? ((pos >= 1) ? prevlast : BLANK) : labs[k - 1];
        const int eprev = (pos >= 1 && pos - 1 < U) ? prev : BLANK;
        skipm[k] = (ext[k] != BLANK && ext[k] != eprev) ? 1.0 : 0.0;
    }

    const float* base = lp + (size_t)b * CCH;
    const size_t rowstride = (size_t)B * CCH;

    float2 rA[FCH], rB[FCH];
    double sblank = 0.0;
    int logz = 0;
    double a[8];
    double a512 = 0.0;
    double G[FCH][4];

    auto issue = [&](float2* r, int chunk) {
#pragma unroll
        for (int i = 0; i < FCH; ++i) {
            int t = chunk * FCH + i;
            t = (t < T) ? t : (T - 1);
            r[i] = *reinterpret_cast<const float2*>(base + (size_t)t * rowstride + 2 * lane);
        }
    };

    auto stage = [&](const float2* r, int buf, int chunk) {
#pragma unroll
        for (int i = 0; i < FCH; ++i) {
            const float2 v = r[i];
            const float lpb = __int_as_float(
                __builtin_amdgcn_readfirstlane(__float_as_int(v.y)));
            const int t = chunk * FCH + i;
            if (t < Tb) sblank += (double)lpb;
            double2 p;
            p.x = (double)__expf(v.x - lpb);
            p.y = (double)__expf(v.y - lpb);
            *reinterpret_cast<double2*>(&pbuf[buf][i][2 * lane]) = p;
        }
    };

    auto gather = [&](int buf) {
#pragma unroll
        for (int r = 0; r < FCH; ++r)
#pragma unroll
            for (int k = 0; k < 4; ++k)
                G[r][k] = pbuf[buf][r][ext[k]];
    };

    auto step = [&](const double* g) {
        const double am1 = dpp_shr1_f64(a[7]);
        a512 += a[7];
        const double n0 = a[0] + am1;
        const double n1 = (a[1] + a[0] + skipm[0] * am1) * g[0];
        const double n2 = a[2] + a[1];
        const double n3 = (a[3] + a[2] + skipm[1] * a[1]) * g[1];
        const double n4 = a[4] + a[3];
        const double n5 = (a[5] + a[4] + skipm[2] * a[3]) * g[2];
        const double n6 = a[6] + a[5];
        const double n7 = (a[7] + a[6] + skipm[3] * a[5]) * g[3];
        a[0] = n0; a[1] = n1; a[2] = n2; a[3] = n3;
        a[4] = n4; a[5] = n5; a[6] = n6; a[7] = n7;
    };

    auto rescale = [&]() {
        double m = fmax(fmax(fmax(a[0], a[1]), fmax(a[2], a[3])),
                        fmax(fmax(a[4], a[5]), fmax(a[6], a[7])));
        int v = __double2hiint(m);
        int t;
        t = __builtin_amdgcn_update_dpp(0, v, 0x111, 0xF, 0xF, true); v = imax(v, t);
        t = __builtin_amdgcn_update_dpp(0, v, 0x112, 0xF, 0xF, true); v = imax(v, t);
        t = __builtin_amdgcn_update_dpp(0, v, 0x114, 0xF, 0xF, true); v = imax(v, t);
        t = __builtin_amdgcn_update_dpp(0, v, 0x118, 0xF, 0xF, true); v = imax(v, t);
        const int m0 = __builtin_amdgcn_readlane(v, 15);
        const int m1 = __builtin_amdgcn_readlane(v, 31);
        const int m2 = __builtin_amdgcn_readlane(v, 47);
        const int m3 = __builtin_amdgcn_readlane(v, 63);
        const int mb = imax(imax(m0, m1), imax(m2, m3));
        const int e11 = (mb >> 20) & 0x7FF;
        if (e11 > 0) {
            const double sc = __hiloint2double((2046 - e11) << 20, 0);
#pragma unroll
            for (int j = 0; j < 8; ++j) a[j] *= sc;
            a512 *= sc;
            logz += e11 - 1023;
        }
    };

    issue(rA, 0);
    issue(rB, 1);
    stage(rA, 0, 0);
    issue(rA, 2);
#pragma unroll
    for (int j = 0; j < 8; ++j) a[j] = 0.0;

    const int nch = (Tb + FCH - 1) / FCH;

    for (int c = 0; c < nch; ++c) {
        const int buf = c & 1;
        gather(buf);
        if (c + 1 < nch) {
            if ((c + 1) & 1) { stage(rB, 1, c + 1); issue(rB, c + 3); }
            else             { stage(rA, 0, c + 1); issue(rA, c + 3); }
        }
        const int t0 = c * FCH;
        if (c == 0) {
            if (lane == 0) { a[0] = 1.0; a[1] = G[0][0]; }
#pragma unroll
            for (int r = 1; r < FCH; ++r) if (r < Tb) step(G[r]);
        } else if (t0 + FCH <= Tb) {
#pragma unroll
            for (int r = 0; r < FCH; ++r) step(G[r]);
        } else {
#pragma unroll
            for (int r = 0; r < FCH; ++r) if (t0 + r < Tb) step(G[r]);
        }
        if ((c & 1) || (c == nch - 1)) rescale();
    }

#pragma unroll
    for (int j = 0; j < 8; ++j) afin[lane * 8 + j] = a[j];
    if (lane == 63) afin[512] = a512;
    __syncthreads();
    if (lane == 0) {
        const int i1 = 2 * U;
        int i2 = 2 * U - 1; if (i2 < 0) i2 = 0;
        const double ssum = afin[i1] + afin[i2];
        const double ll = log(ssum) + sblank + (double)logz * 0.6931471805599453;
        perb[b] = (float)(-ll);
    }
}

__global__ void reduce_sum(const float* __restrict__ perb, float* __restrict__ out, int B)
{
    const int lane = threadIdx.x;
    float v = 0.0f;
    for (int i = lane; i < B; i += 64) v += perb[i];
#pragma unroll
    for (int off = 32; off >= 1; off >>= 1) v += __shfl_xor(v, off);
    if (lane == 0) out[0] = v;
}

} // namespace

extern "C" void kernel_launch(void* const* d_in, const int* in_sizes, int n_in,
                              void* d_out, int out_size, void* d_ws, size_t ws_size,
                              hipStream_t stream)
{
    const float* lp  = (const float*)d_in[0];   // [T,B,C] log-softmax, f32
    const int* ilen  = (const int*)d_in[1];     // [B]
    const int* tgt   = (const int*)d_in[2];     // [B,L]
    const int* tlen  = (const int*)d_in[3];     // [B]

    const int B = in_sizes[1];
    const int L = in_sizes[2] / B;
    const int T = in_sizes[0] / (B * CCH);

    const size_t gbytes = (size_t)B * T * 256 * sizeof(float);
    const size_t lbytes = (size_t)B * T * sizeof(float);
    const size_t need   = gbytes + lbytes + (size_t)B * sizeof(float);

    if (ws_size >= need && L == 256 && (T % GT) == 0) {
        float* gout   = (float*)d_ws;
        float* lpbout = (float*)((char*)d_ws + gbytes);
        float* perb   = (float*)((char*)d_ws + gbytes + lbytes);
        dim3 g1(T / GT, B);
        ctc_gather<<<g1, 256, 0, stream>>>(lp, tgt, tlen, gout, lpbout, T, B, L);
        ctc_scan<<<B, 64, 0, stream>>>(gout, lpbout, ilen, tgt, tlen, perb, T, B, L);
        reduce_sum<<<1, 64, 0, stream>>>(perb, (float*)d_out, B);
    } else {
        float* perb = (float*)d_ws;
        ctc_fwd<<<B, 64, 0, stream>>>(lp, ilen, tgt, tlen, perb, T, B, L);
        reduce_sum<<<1, 64, 0, stream>>>(perb, (float*)d_out, B);
    }
}

// Round 5
// 180.920 us; speedup vs baseline: 2.9341x; 1.0216x over previous
//
#include <hip/hip_runtime.h>
#include <math.h>

namespace {

constexpr int CCH = 128;   // classes
constexpr int BLANK = 1;
constexpr int CH = 8;      // scan steps per chunk (register double-buffer)
constexpr int GT = 8;      // pass-1 time rows per block

__device__ __forceinline__ int imax(int a, int b) { return a > b ? a : b; }
__device__ __forceinline__ int imin(int a, int b) { return a < b ? a : b; }

// lane i <- lane i-1 (lane 0 <- 0.0), pure VALU (DPP wave_shr:1)
__device__ __forceinline__ double dpp_shr1_f64(double x) {
    int lo = __double2loint(x), hi = __double2hiint(x);
    lo = __builtin_amdgcn_update_dpp(0, lo, 0x138, 0xF, 0xF, true);
    hi = __builtin_amdgcn_update_dpp(0, hi, 0x138, 0xF, 0xF, true);
    return __hiloint2double(hi, lo);
}

// ---------------- pass 1: parallel gather/exp ----------------
__global__ __launch_bounds__(256)
void ctc_gather(const float* __restrict__ lp,
                const int* __restrict__ tgt,
                const int* __restrict__ tlen,
                float* __restrict__ gout,   // [B][T][256]
                float* __restrict__ lpbout, // [B][T]
                int T, int B, int L)
{
    const int b   = blockIdx.y;
    const int t0  = blockIdx.x * GT;
    const int tid = threadIdx.x;

    __shared__ int   sTgt[256];
    __shared__ float sLp[GT][CCH];

    int U = tlen[b]; if (U < 0) U = 0; if (U > L) U = L;

    sTgt[tid] = tgt[(size_t)b * L + tid];
    {
        const int idx = tid * 4;
        const int r = idx >> 7, col = idx & 127;
        *reinterpret_cast<float4*>(&sLp[r][col]) =
            *reinterpret_cast<const float4*>(lp + ((size_t)(t0 + r) * B + b) * CCH + col);
    }
    __syncthreads();

    const int r = tid >> 5;          // 0..7 : time row
    const int c = tid & 31;          // 0..31: position group
    const float blankv = sLp[r][BLANK];
    float g[8];
#pragma unroll
    for (int k = 0; k < 8; ++k) {
        const int p = c * 8 + k;
        const int lab = (p < U) ? (sTgt[p] & 127) : BLANK;
        g[k] = __expf(sLp[r][lab] - blankv);   // pos>=U -> expf(0)=1 exactly
    }
    float* dst = gout + ((size_t)b * T + (t0 + r)) * 256 + c * 8;
    *reinterpret_cast<float4*>(dst)     = make_float4(g[0], g[1], g[2], g[3]);
    *reinterpret_cast<float4*>(dst + 4) = make_float4(g[4], g[5], g[6], g[7]);
    if (tid < GT) lpbout[(size_t)b * T + t0 + tid] = sLp[tid][BLANK];
}

// ---------------- pass 2: serial scan, no LDS in hot loop ----------------
__global__ __launch_bounds__(64, 1)
void ctc_scan(const float* __restrict__ gg,   // [B][T][256]
              const float* __restrict__ lpb,  // [B][T]
              const int* __restrict__ ilen,
              const int* __restrict__ tgt,
              const int* __restrict__ tlen,
              float* __restrict__ perb,
              int T, int B, int L)
{
    const int b = blockIdx.x;
    const int lane = threadIdx.x;
    int Tb = ilen[b]; if (Tb < 1) Tb = 1; if (Tb > T) Tb = T;
    int U  = tlen[b]; if (U < 0) U = 0;   if (U > L) U = L;

    __shared__ double afin[514];

    // ---- per-lane skip masks (pos = lane*4 + k) ----
    const int4 lab4 = *reinterpret_cast<const int4*>(tgt + (size_t)b * L + lane * 4);
    const int labs[4] = {lab4.x, lab4.y, lab4.z, lab4.w};
    const int prevlast = __shfl_up(labs[3], 1);
    double skipm[4];
#pragma unroll
    for (int k = 0; k < 4; ++k) {
        const int pos = lane * 4 + k;
        const int e = (pos < U) ? labs[k] : BLANK;
        const int prevraw = (k == 0) ? ((pos >= 1) ? prevlast : BLANK) : labs[k - 1];
        const int eprev = (pos >= 1 && pos - 1 < U) ? prevraw : BLANK;
        skipm[k] = (e != BLANK && e != eprev) ? 1.0 : 0.0;
    }

    const float* gb = gg + (size_t)b * T * 256 + lane * 4;
    const int maxch = T / CH - 1;    // T % CH == 0 guaranteed by launch guard

    double a[8];
#pragma unroll
    for (int j = 0; j < 8; ++j) a[j] = 0.0;
    double a512 = 0.0;     // lane 63's copy = alpha[512]
    int logz = 0;

    float4 GA[CH], GB[CH];

    auto issue = [&](float4* Gx, int chunk) {
        const float* p = gb + (size_t)imin(chunk, maxch) * (CH * 256);
#pragma unroll
        for (int r = 0; r < CH; ++r)
            Gx[r] = *reinterpret_cast<const float4*>(p + r * 256);
        __builtin_amdgcn_sched_barrier(0);   // pin loads here: keep prefetch early
    };

    auto step = [&](const float4 gf) {
        const double g0 = (double)gf.x, g1 = (double)gf.y,
                     g2 = (double)gf.z, g3 = (double)gf.w;
        const double am1 = dpp_shr1_f64(a[7]);   // alpha[s0-1] (lane0 -> 0)
        a512 += a[7];                            // pre-update a[7] (lane63 = alpha[511])
        const double n0 = a[0] + am1;
        const double n1 = (a[1] + a[0] + skipm[0] * am1) * g0;
        const double n2 = a[2] + a[1];
        const double n3 = (a[3] + a[2] + skipm[1] * a[1]) * g1;
        const double n4 = a[4] + a[3];
        const double n5 = (a[5] + a[4] + skipm[2] * a[3]) * g2;
        const double n6 = a[6] + a[5];
        const double n7 = (a[7] + a[6] + skipm[3] * a[5]) * g3;
        a[0] = n0; a[1] = n1; a[2] = n2; a[3] = n3;
        a[4] = n4; a[5] = n5; a[6] = n6; a[7] = n7;
    };

    // exact power-of-2 rescale; max via f64 hi-word int reduce (no LDS)
    auto rescale = [&]() {
        double m = fmax(fmax(fmax(a[0], a[1]), fmax(a[2], a[3])),
                        fmax(fmax(a[4], a[5]), fmax(a[6], a[7])));
        int v = __double2hiint(m);               // nonneg doubles: hi-word order = fp order
        int t;
        t = __builtin_amdgcn_update_dpp(0, v, 0x111, 0xF, 0xF, true); v = imax(v, t);
        t = __builtin_amdgcn_update_dpp(0, v, 0x112, 0xF, 0xF, true); v = imax(v, t);
        t = __builtin_amdgcn_update_dpp(0, v, 0x114, 0xF, 0xF, true); v = imax(v, t);
        t = __builtin_amdgcn_update_dpp(0, v, 0x118, 0xF, 0xF, true); v = imax(v, t);
        const int m0 = __builtin_amdgcn_readlane(v, 15);
        const int m1 = __builtin_amdgcn_readlane(v, 31);
        const int m2 = __builtin_amdgcn_readlane(v, 47);
        const int m3 = __builtin_amdgcn_readlane(v, 63);
        const int mb = imax(imax(m0, m1), imax(m2, m3));
        const int e11 = (mb >> 20) & 0x7FF;
        if (e11 > 0) {
            const double sc = __hiloint2double((2046 - e11) << 20, 0);  // 2^(1023-e11)
#pragma unroll
            for (int j = 0; j < 8; ++j) a[j] *= sc;
            a512 *= sc;
            logz += e11 - 1023;
        }
    };

    auto chunk = [&](float4 (&Gx)[CH], int c) {
        const int t0 = c * CH;
        if (c == 0) {
            if (lane == 0) { a[0] = 1.0; a[1] = (double)Gx[0].x; }  // t=0 init
#pragma unroll
            for (int r = 1; r < CH; ++r) if (r < Tb) step(Gx[r]);
        } else if (t0 + CH <= Tb) {
#pragma unroll
            for (int r = 0; r < CH; ++r) step(Gx[r]);               // fast path
        } else {
#pragma unroll
            for (int r = 0; r < CH; ++r) if (t0 + r < Tb) step(Gx[r]);
        }
    };

    const int nch = (Tb + CH - 1) / CH;

    issue(GA, 0);
    issue(GB, 1);

    for (int c = 0; c < nch; c += 2) {
        chunk(GA, c);
        issue(GA, c + 2);
        if (c + 1 < nch) {
            chunk(GB, c + 1);
            issue(GB, c + 3);
        }
        rescale();   // every 16 steps (exact pow-2: bit-identical result)
    }

    // ---- epilogue ----
#pragma unroll
    for (int j = 0; j < 8; ++j) afin[lane * 8 + j] = a[j];
    if (lane == 63) afin[512] = a512;

    // sblank: coalesced read of lpb, deterministic butterfly reduce (f64)
    double sb = 0.0;
    const float* lbp = lpb + (size_t)b * T;
    for (int i = lane; i < T; i += 64)
        if (i < Tb) sb += (double)lbp[i];
#pragma unroll
    for (int off = 32; off >= 1; off >>= 1) sb += __shfl_xor(sb, off);

    __syncthreads();
    if (lane == 0) {
        const int i1 = 2 * U;
        int i2 = 2 * U - 1; if (i2 < 0) i2 = 0;
        const double ssum = afin[i1] + afin[i2];
        const double ll = log(ssum) + sb + (double)logz * 0.6931471805599453;
        perb[b] = (float)(-ll);
    }
}

// ---------------- fallback: proven round-3 single-kernel path ----------------
constexpr int FCH = 8;
constexpr int ROWD = 128;

__global__ __launch_bounds__(64, 1)
void ctc_fwd(const float* __restrict__ lp,
             const int* __restrict__ ilen,
             const int* __restrict__ tgt,
             const int* __restrict__ tlen,
             float* __restrict__ perb,
             int T, int B, int L)
{
    const int b = blockIdx.x;
    const int lane = threadIdx.x;
    int Tb = ilen[b]; if (Tb < 1) Tb = 1; if (Tb > T) Tb = T;
    int U  = tlen[b]; if (U < 0) U = 0;   if (U > L) U = L;

    __shared__ double pbuf[2][FCH][ROWD];
    __shared__ double afin[2 * 256 + 2];

    const int4 lab4 = *reinterpret_cast<const int4*>(tgt + (size_t)b * L + lane * 4);
    const int labs[4] = {lab4.x, lab4.y, lab4.z, lab4.w};
    const int prevlast = __shfl_up(labs[3], 1);
    int ext[4];
    double skipm[4];
#pragma unroll
    for (int k = 0; k < 4; ++k) {
        const int pos = lane * 4 + k;
        ext[k] = (pos < U) ? labs[k] : BLANK;
        const int prev = (k == 0) ? ((pos >= 1) ? prevlast : BLANK) : labs[k - 1];
        const int eprev = (pos >= 1 && pos - 1 < U) ? prev : BLANK;
        skipm[k] = (ext[k] != BLANK && ext[k] != eprev) ? 1.0 : 0.0;
    }

    const float* base = lp + (size_t)b * CCH;
    const size_t rowstride = (size_t)B * CCH;

    float2 rA[FCH], rB[FCH];
    double sblank = 0.0;
    int logz = 0;
    double a[8];
    double a512 = 0.0;
    double G[FCH][4];

    auto issue = [&](float2* r, int chunk) {
#pragma unroll
        for (int i = 0; i < FCH; ++i) {
            int t = chunk * FCH + i;
            t = (t < T) ? t : (T - 1);
            r[i] = *reinterpret_cast<const float2*>(base + (size_t)t * rowstride + 2 * lane);
        }
    };

    auto stage = [&](const float2* r, int buf, int chunk) {
#pragma unroll
        for (int i = 0; i < FCH; ++i) {
            const float2 v = r[i];
            const float lpb = __int_as_float(
                __builtin_amdgcn_readfirstlane(__float_as_int(v.y)));
            const int t = chunk * FCH + i;
            if (t < Tb) sblank += (double)lpb;
            double2 p;
            p.x = (double)__expf(v.x - lpb);
            p.y = (double)__expf(v.y - lpb);
            *reinterpret_cast<double2*>(&pbuf[buf][i][2 * lane]) = p;
        }
    };

    auto gather = [&](int buf) {
#pragma unroll
        for (int r = 0; r < FCH; ++r)
#pragma unroll
            for (int k = 0; k < 4; ++k)
                G[r][k] = pbuf[buf][r][ext[k]];
    };

    auto step = [&](const double* g) {
        const double am1 = dpp_shr1_f64(a[7]);
        a512 += a[7];
        const double n0 = a[0] + am1;
        const double n1 = (a[1] + a[0] + skipm[0] * am1) * g[0];
        const double n2 = a[2] + a[1];
        const double n3 = (a[3] + a[2] + skipm[1] * a[1]) * g[1];
        const double n4 = a[4] + a[3];
        const double n5 = (a[5] + a[4] + skipm[2] * a[3]) * g[2];
        const double n6 = a[6] + a[5];
        const double n7 = (a[7] + a[6] + skipm[3] * a[5]) * g[3];
        a[0] = n0; a[1] = n1; a[2] = n2; a[3] = n3;
        a[4] = n4; a[5] = n5; a[6] = n6; a[7] = n7;
    };

    auto rescale = [&]() {
        double m = fmax(fmax(fmax(a[0], a[1]), fmax(a[2], a[3])),
                        fmax(fmax(a[4], a[5]), fmax(a[6], a[7])));
        int v = __double2hiint(m);
        int t;
        t = __builtin_amdgcn_update_dpp(0, v, 0x111, 0xF, 0xF, true); v = imax(v, t);
        t = __builtin_amdgcn_update_dpp(0, v, 0x112, 0xF, 0xF, true); v = imax(v, t);
        t = __builtin_amdgcn_update_dpp(0, v, 0x114, 0xF, 0xF, true); v = imax(v, t);
        t = __builtin_amdgcn_update_dpp(0, v, 0x118, 0xF, 0xF, true); v = imax(v, t);
        const int m0 = __builtin_amdgcn_readlane(v, 15);
        const int m1 = __builtin_amdgcn_readlane(v, 31);
        const int m2 = __builtin_amdgcn_readlane(v, 47);
        const int m3 = __builtin_amdgcn_readlane(v, 63);
        const int mb = imax(imax(m0, m1), imax(m2, m3));
        const int e11 = (mb >> 20) & 0x7FF;
        if (e11 > 0) {
            const double sc = __hiloint2double((2046 - e11) << 20, 0);
#pragma unroll
            for (int j = 0; j < 8; ++j) a[j] *= sc;
            a512 *= sc;
            logz += e11 - 1023;
        }
    };

    issue(rA, 0);
    issue(rB, 1);
    stage(rA, 0, 0);
    issue(rA, 2);
#pragma unroll
    for (int j = 0; j < 8; ++j) a[j] = 0.0;

    const int nch = (Tb + FCH - 1) / FCH;

    for (int c = 0; c < nch; ++c) {
        const int buf = c & 1;
        gather(buf);
        if (c + 1 < nch) {
            if ((c + 1) & 1) { stage(rB, 1, c + 1); issue(rB, c + 3); }
            else             { stage(rA, 0, c + 1); issue(rA, c + 3); }
        }
        const int t0 = c * FCH;
        if (c == 0) {
            if (lane == 0) { a[0] = 1.0; a[1] = G[0][0]; }
#pragma unroll
            for (int r = 1; r < FCH; ++r) if (r < Tb) step(G[r]);
        } else if (t0 + FCH <= Tb) {
#pragma unroll
            for (int r = 0; r < FCH; ++r) step(G[r]);
        } else {
#pragma unroll
            for (int r = 0; r < FCH; ++r) if (t0 + r < Tb) step(G[r]);
        }
        if ((c & 1) || (c == nch - 1)) rescale();
    }

#pragma unroll
    for (int j = 0; j < 8; ++j) afin[lane * 8 + j] = a[j];
    if (lane == 63) afin[512] = a512;
    __syncthreads();
    if (lane == 0) {
        const int i1 = 2 * U;
        int i2 = 2 * U - 1; if (i2 < 0) i2 = 0;
        const double ssum = afin[i1] + afin[i2];
        const double ll = log(ssum) + sblank + (double)logz * 0.6931471805599453;
        perb[b] = (float)(-ll);
    }
}

__global__ void reduce_sum(const float* __restrict__ perb, float* __restrict__ out, int B)
{
    const int lane = threadIdx.x;
    float v = 0.0f;
    for (int i = lane; i < B; i += 64) v += perb[i];
#pragma unroll
    for (int off = 32; off >= 1; off >>= 1) v += __shfl_xor(v, off);
    if (lane == 0) out[0] = v;
}

} // namespace

extern "C" void kernel_launch(void* const* d_in, const int* in_sizes, int n_in,
                              void* d_out, int out_size, void* d_ws, size_t ws_size,
                              hipStream_t stream)
{
    const float* lp  = (const float*)d_in[0];   // [T,B,C] log-softmax, f32
    const int* ilen  = (const int*)d_in[1];     // [B]
    const int* tgt   = (const int*)d_in[2];     // [B,L]
    const int* tlen  = (const int*)d_in[3];     // [B]

    const int B = in_sizes[1];
    const int L = in_sizes[2] / B;
    const int T = in_sizes[0] / (B * CCH);

    const size_t gbytes = (size_t)B * T * 256 * sizeof(float);
    const size_t lbytes = (size_t)B * T * sizeof(float);
    const size_t need   = gbytes + lbytes + (size_t)B * sizeof(float);

    if (ws_size >= need && L == 256 && (T % GT) == 0) {
        float* gout   = (float*)d_ws;
        float* lpbout = (float*)((char*)d_ws + gbytes);
        float* perb   = (float*)((char*)d_ws + gbytes + lbytes);
        dim3 g1(T / GT, B);
        ctc_gather<<<g1, 256, 0, stream>>>(lp, tgt, tlen, gout, lpbout, T, B, L);
        ctc_scan<<<B, 64, 0, stream>>>(gout, lpbout, ilen, tgt, tlen, perb, T, B, L);
        reduce_sum<<<1, 64, 0, stream>>>(perb, (float*)d_out, B);
    } else {
        float* perb = (float*)d_ws;
        ctc_fwd<<<B, 64, 0, stream>>>(lp, ilen, tgt, tlen, perb, T, B, L);
        reduce_sum<<<1, 64, 0, stream>>>(perb, (float*)d_out, B);
    }
}